// Round 12
// baseline (23898.729 us; speedup 1.0000x reference)
//
#include <hip/hip_runtime.h>
#include <math.h>

// Round 12: R9's np-float32 c_einsum bit-model, with the argmax key taken on
// the RAW f32 sim (pre-sigmoid). Rationale: f32 sigmoid collapses sims within
// ~3e-7 into bit-equal values; argmax-after-sigmoid -> first of collision
// class, argmax-before -> true max. The np reference evidently uses the
// pre-sigmoid ordering (monotone "optimization"); ~15 collision pixels explain
// the stable 0.1156/0.1299 plateau of all prior rounds.
//
// Geometry: n=8, c=256, h=128, w=128, D1=512; FC=8, FH=FW=2, CS=8
// sc=64, scv=32, sh=sw=64, m=256, l=4096, s=64

__device__ __forceinline__ float tree8(const float* a) {
    float t01 = __fadd_rn(a[0], a[1]);
    float t23 = __fadd_rn(a[2], a[3]);
    float t45 = __fadd_rn(a[4], a[5]);
    float t67 = __fadd_rn(a[6], a[7]);
    return __fadd_rn(__fadd_rn(t01, t23), __fadd_rn(t45, t67));
}
__device__ __forceinline__ float pw32(const float* a) {
    float r[8];
    #pragma unroll
    for (int j = 0; j < 8; ++j) r[j] = a[j];
    #pragma unroll
    for (int i = 8; i < 32; i += 8) {
        #pragma unroll
        for (int j = 0; j < 8; ++j) r[j] = __fadd_rn(r[j], a[i + j]);
    }
    float t01 = __fadd_rn(r[0], r[1]);
    float t23 = __fadd_rn(r[2], r[3]);
    float t45 = __fadd_rn(r[4], r[5]);
    float t67 = __fadd_rn(r[6], r[7]);
    return __fadd_rn(__fadd_rn(t01, t23), __fadd_rn(t45, t67));
}
// c_einsum contig dot (SSE, no FMA), n=32: stride-4 lanes, reduce (s0+s1)+(s2+s3)
__device__ __forceinline__ float dot32_sse(const float* a, const float* b) {
    float s0 = 0.f, s1 = 0.f, s2 = 0.f, s3 = 0.f;
    #pragma unroll
    for (int k = 0; k < 32; k += 4) {
        s0 = __fadd_rn(s0, __fmul_rn(a[k + 0], b[k + 0]));
        s1 = __fadd_rn(s1, __fmul_rn(a[k + 1], b[k + 1]));
        s2 = __fadd_rn(s2, __fmul_rn(a[k + 2], b[k + 2]));
        s3 = __fadd_rn(s3, __fmul_rn(a[k + 3], b[k + 3]));
    }
    return __fadd_rn(__fadd_rn(s0, s1), __fadd_rn(s2, s3));
}

// ---- kCB: centers. One block per (m,s); thread = channel (64). ----
__global__ __launch_bounds__(64) void kCB(
    const float* __restrict__ x, const float* __restrict__ Wp,
    const float* __restrict__ bp, float* __restrict__ CB)
{
    __shared__ float xs[256][64];     // [c][pixel a*8+b]  64 KiB
    int bidx = blockIdx.x;            // m*64 + s
    int m = bidx >> 6, s = bidx & 63;
    int fw = m & 1, fh = (m >> 1) & 1, fc = (m >> 2) & 7, n = m >> 5;
    int ci = s >> 3, cj = s & 7;
    int t = threadIdx.x;
    for (int i = t; i < 256 * 64; i += 64) {
        int c = i >> 6, p = i & 63;
        int a = p >> 3, b2 = p & 7;
        int hh = fh * 64 + ci * 8 + a, ww = fw * 64 + cj * 8 + b2;
        xs[c][p] = x[((size_t)(n * 256 + c) * 128 + hh) * 128 + ww];
    }
    __syncthreads();
    int ch = t;
    const float* wr = Wp + (size_t)(fc * 64 + ch) * 256;
    float bb = bp[fc * 64 + ch];
    float total = 0.f;
    for (int a = 0; a < 8; ++a) {
        float yb[8];
        #pragma unroll
        for (int b2 = 0; b2 < 8; ++b2) {
            float acc = 0.f;          // c_einsum saxpy: sequential c, mul+add
            for (int c = 0; c < 256; ++c)
                acc = __fadd_rn(acc, __fmul_rn(wr[c], xs[c][a * 8 + b2]));
            yb[b2] = __fadd_rn(acc, bb);
        }
        float tr = tree8(yb);
        total = (a == 0) ? tr : __fadd_rn(total, tr);
    }
    CB[((size_t)m * 64 + s) * 64 + ch] = __fdiv_rn(total, 64.0f);
}

// ---- kNC: normalized center point: square, pw32, sqrt, max, div ----
__global__ __launch_bounds__(64) void kNC(
    const float* __restrict__ CB, float* __restrict__ NCB)
{
    int m = blockIdx.x, s = threadIdx.x;
    const float* row = CB + ((size_t)m * 64 + s) * 64;
    float sq[32];
    #pragma unroll
    for (int k = 0; k < 32; ++k) sq[k] = __fmul_rn(row[k], row[k]);
    float n2 = pw32(sq);
    float nr = __fsqrt_rn(n2);
    float mx = fmaxf(nr, 1e-12f);
    #pragma unroll
    for (int k = 0; k < 32; ++k)
        NCB[((size_t)m * 64 + s) * 32 + k] = __fdiv_rn(row[k], mx);
}

// ---- kSim: y_pt (seq mul+add + bias), pw32 norm, f32 div, 64 SSE dots;
//      argmax key = RAW sim (first-max); mv = f32 sigmoid chain at best sim ----
__global__ __launch_bounds__(256) void kSim(
    const float* __restrict__ x, const float* __restrict__ Wp,
    const float* __restrict__ bp, const float* __restrict__ NCB,
    const float* __restrict__ alphap, const float* __restrict__ betap,
    float* __restrict__ MAXV, int* __restrict__ MAXI)
{
    __shared__ float wpl[32][256];    // 32 KiB
    __shared__ float ncl[64 * 32];    // 8 KiB
    int b = blockIdx.x;               // 1024 = m*4 + q
    int m = b >> 2, q = b & 3;
    int fw = m & 1, fh = (m >> 1) & 1, fc = (m >> 2) & 7, n = m >> 5;
    int t = threadIdx.x;
    for (int i = t; i < 32 * 256; i += 256) {
        int k = i >> 8, c = i & 255;
        wpl[k][c] = Wp[(size_t)(fc * 64 + k) * 256 + c];
    }
    for (int i = t; i < 2048; i += 256) ncl[i] = NCB[(size_t)m * 2048 + i];
    __syncthreads();

    float al = alphap[0], be = betap[0];
    for (int it = 0; it < 4; ++it) {
        int l = q * 1024 + it * 256 + t;
        int sh = l >> 6, sw = l & 63;
        int hh = fh * 64 + sh, ww = fw * 64 + sw;
        const float* pxp = x + (((size_t)(n * 256) * 128 + hh) * 128 + ww);
        float xp[32];
        #pragma unroll
        for (int k = 0; k < 32; ++k) xp[k] = 0.f;
        for (int c = 0; c < 256; ++c) {
            float xv = pxp[(size_t)c * 16384];
            #pragma unroll
            for (int k = 0; k < 32; ++k)
                xp[k] = __fadd_rn(xp[k], __fmul_rn(wpl[k][c], xv));
        }
        #pragma unroll
        for (int k = 0; k < 32; ++k) xp[k] = __fadd_rn(xp[k], bp[fc * 64 + k]);
        float sq[32];
        #pragma unroll
        for (int k = 0; k < 32; ++k) sq[k] = __fmul_rn(xp[k], xp[k]);
        float nr = __fsqrt_rn(pw32(sq));
        float mx = fmaxf(nr, 1e-12f);
        float nx[32];
        #pragma unroll
        for (int k = 0; k < 32; ++k) nx[k] = __fdiv_rn(xp[k], mx);

        // argmax over RAW f32 sims (pre-sigmoid), first-max on ties
        float best = -3.0e38f; int bi = 0;
        for (int s = 0; s < 64; ++s) {
            float dot = dot32_sse(nx, ncl + s * 32);
            if (dot > best) { best = dot; bi = s; }
        }
        // mv = f32 sigmoid chain at the selected sim
        float z = __fadd_rn(__fmul_rn(al, best), be);
        float e = (float)exp(-(double)z);
        float den = __fadd_rn(1.0f, e);
        float sv = __fdiv_rn(1.0f, den);
        MAXV[(size_t)m * 4096 + l] = sv;
        MAXI[(size_t)m * 4096 + l] = bi;
    }
}

// ---- kAgg: one block per (m,s), lanes = value channels; l-ascending scan ----
__global__ __launch_bounds__(64) void kAgg(
    const float* __restrict__ x, const float* __restrict__ Wp,
    const float* __restrict__ bp, const float* __restrict__ CB,
    const float* __restrict__ MAXV, const int* __restrict__ MAXI,
    float* __restrict__ AGG)
{
    __shared__ float wvl[32][256];    // 32 KiB
    int bidx = blockIdx.x;            // m*64 + s
    int m = bidx >> 6, s = bidx & 63;
    int fw = m & 1, fh = (m >> 1) & 1, fc = (m >> 2) & 7, n = m >> 5;
    int t = threadIdx.x;
    for (int i = t; i < 32 * 256; i += 64) {
        int k = i >> 8, c = i & 255;
        wvl[k][c] = Wp[(size_t)(fc * 64 + 32 + k) * 256 + c];
    }
    __syncthreads();
    int v = t;                        // lanes 0..31 active
    float acc = 0.f, accw = 1.0f, bb = 0.f;
    if (v < 32) {
        acc = CB[((size_t)m * 64 + s) * 64 + 32 + v];
        bb = bp[fc * 64 + 32 + v];
    }
    const float* mvp = MAXV + (size_t)m * 4096;
    const int* mip = MAXI + (size_t)m * 4096;
    for (int l = 0; l < 4096; ++l) {
        if (mip[l] == s) {
            float mv = mvp[l];
            if (v < 32) {
                int sh = l >> 6, sw = l & 63;
                int hh = fh * 64 + sh, ww = fw * 64 + sw;
                const float* pxp = x + (((size_t)(n * 256) * 128 + hh) * 128 + ww);
                float yv = 0.f;
                for (int c = 0; c < 256; ++c)
                    yv = __fadd_rn(yv, __fmul_rn(wvl[v][c], pxp[(size_t)c * 16384]));
                yv = __fadd_rn(yv, bb);
                acc = __fadd_rn(acc, __fmul_rn(mv, yv));
            }
            accw = __fadd_rn(accw, mv);
        }
    }
    if (v < 32)
        AGG[((size_t)m * 64 + s) * 32 + v] = __fdiv_rn(acc, accw);
}

// ---- kOut: disp = mv*agg[idx]; out = seq mul+add einsum + bm ----
__global__ __launch_bounds__(256) void kOut(
    const float* __restrict__ AGG, const float* __restrict__ MAXV,
    const int* __restrict__ MAXI, const float* __restrict__ Wm,
    const float* __restrict__ bm, float* __restrict__ out)
{
    __shared__ float dsp[256 * 64];   // [c2 = fc*32+v][px]  64 KiB
    int b = blockIdx.x;               // 2048 = n*256 + h*2 + fw
    int n = b >> 8; int rem = b & 255;
    int h = rem >> 1, fw = rem & 1;
    int fh = h >> 6, sh = h & 63;
    int t = threadIdx.x;
    for (int rep = 0; rep < 2; ++rep) {
        int pair = rep * 256 + t;     // fc(8) * px(64)
        int fc = pair >> 6, px = pair & 63;
        int m = ((n * 8 + fc) * 2 + fh) * 2 + fw;
        int l = sh * 64 + px;
        float mv = MAXV[(size_t)m * 4096 + l];
        int s = MAXI[(size_t)m * 4096 + l];
        const float* ar = AGG + ((size_t)m * 64 + s) * 32;
        #pragma unroll
        for (int v = 0; v < 32; ++v)
            dsp[(fc * 32 + v) * 64 + px] = __fmul_rn(mv, ar[v]);
    }
    __syncthreads();
    int d = t;
    float a[64];
    #pragma unroll
    for (int p = 0; p < 64; ++p) a[p] = 0.f;
    const float* wr = Wm + (size_t)d * 256;
    for (int c = 0; c < 256; ++c) {
        float wv = wr[c];
        const float* row = dsp + c * 64;
        #pragma unroll
        for (int p = 0; p < 64; ++p)
            a[p] = __fadd_rn(a[p], __fmul_rn(wv, row[p]));
    }
    float bb = bm[d];
    float* orow = out + ((size_t)(n * 256 + d) * 128 + h) * 128 + fw * 64;
    for (int p = 0; p < 64; ++p)
        orow[p] = __fadd_rn(a[p], bb);
}

extern "C" void kernel_launch(void* const* d_in, const int* in_sizes, int n_in,
                              void* d_out, int out_size, void* d_ws, size_t ws_size,
                              hipStream_t stream)
{
    const float* x     = (const float*)d_in[0];
    const float* Wp    = (const float*)d_in[1];
    const float* bp    = (const float*)d_in[2];
    const float* Wm    = (const float*)d_in[3];
    const float* bm    = (const float*)d_in[4];
    const float* alpha = (const float*)d_in[5];
    const float* beta  = (const float*)d_in[6];
    float* out = (float*)d_out;

    float* CB   = (float*)d_ws;                   // 1048576
    float* NCB  = CB + 1048576;                   // 524288
    float* MAXV = NCB + 524288;                   // 1048576
    int*   MAXI = (int*)(MAXV + 1048576);         // 1048576
    float* AGG  = (float*)(MAXI + 1048576);       // 524288

    hipLaunchKernelGGL(kCB,  dim3(16384), dim3(64),  0, stream, x, Wp, bp, CB);
    hipLaunchKernelGGL(kNC,  dim3(256),   dim3(64),  0, stream, CB, NCB);
    hipLaunchKernelGGL(kSim, dim3(1024),  dim3(256), 0, stream, x, Wp, bp, NCB, alpha, beta, MAXV, MAXI);
    hipLaunchKernelGGL(kAgg, dim3(16384), dim3(64),  0, stream, x, Wp, bp, CB, MAXV, MAXI, AGG);
    hipLaunchKernelGGL(kOut, dim3(2048),  dim3(256), 0, stream, AGG, MAXV, MAXI, Wm, bm, out);
}

// Round 13
// 9093.671 us; speedup vs baseline: 2.6281x; 2.6281x over previous
//
#include <hip/hip_runtime.h>
#include <math.h>

// Round 13 = Round 12 (PASSED) + performance:
//  - kAgg: serial-scan (15.4 ms, 10% occupancy, 2e9 bank conflicts) replaced by
//    per-m parallel scatter with LDS atomics. Value path: order-free, FMA OK.
//  - kCB: same bit-exact arithmetic chain, remapped to 256 threads/block.
//  - kSim/kNC/kOut: verbatim from round 12 (ordering path: bit-frozen).
//
// ORDERING-PATH INVARIANT (do not change): y_pt = seq-c mul+add + f32 bias;
// center = seq-c dot, tree8 over b, left-fold over a, /64; norms = pw32;
// nx/nc = f32 div; sim = dot32 stride-4 lanes reduce (s0+s1)+(s2+s3);
// argmax = FIRST max over RAW f32 sims; mv = f32 sigmoid chain (CR exp).
//
// Geometry: n=8, c=256, h=128, w=128; FC=8, FH=FW=2, CS=8
// sc=64, scv=32, sh=sw=64, m=256, l=4096, s=64

__device__ __forceinline__ float tree8(const float* a) {
    float t01 = __fadd_rn(a[0], a[1]);
    float t23 = __fadd_rn(a[2], a[3]);
    float t45 = __fadd_rn(a[4], a[5]);
    float t67 = __fadd_rn(a[6], a[7]);
    return __fadd_rn(__fadd_rn(t01, t23), __fadd_rn(t45, t67));
}
__device__ __forceinline__ float pw32(const float* a) {
    float r[8];
    #pragma unroll
    for (int j = 0; j < 8; ++j) r[j] = a[j];
    #pragma unroll
    for (int i = 8; i < 32; i += 8) {
        #pragma unroll
        for (int j = 0; j < 8; ++j) r[j] = __fadd_rn(r[j], a[i + j]);
    }
    float t01 = __fadd_rn(r[0], r[1]);
    float t23 = __fadd_rn(r[2], r[3]);
    float t45 = __fadd_rn(r[4], r[5]);
    float t67 = __fadd_rn(r[6], r[7]);
    return __fadd_rn(__fadd_rn(t01, t23), __fadd_rn(t45, t67));
}
__device__ __forceinline__ float dot32_sse(const float* a, const float* b) {
    float s0 = 0.f, s1 = 0.f, s2 = 0.f, s3 = 0.f;
    #pragma unroll
    for (int k = 0; k < 32; k += 4) {
        s0 = __fadd_rn(s0, __fmul_rn(a[k + 0], b[k + 0]));
        s1 = __fadd_rn(s1, __fmul_rn(a[k + 1], b[k + 1]));
        s2 = __fadd_rn(s2, __fmul_rn(a[k + 2], b[k + 2]));
        s3 = __fadd_rn(s3, __fmul_rn(a[k + 3], b[k + 3]));
    }
    return __fadd_rn(__fadd_rn(s0, s1), __fadd_rn(s2, s3));
}

// ---- kCB: centers, bit-exact chain, 256 threads (4 a-pairs in parallel) ----
__global__ __launch_bounds__(256) void kCB(
    const float* __restrict__ x, const float* __restrict__ Wp,
    const float* __restrict__ bp, float* __restrict__ CB)
{
    __shared__ float xs[256][64];     // [c][pixel a*8+b]  64 KiB
    __shared__ float tra[64][8];      // per-(ch) tree8 results per a (2 KiB)
    int bidx = blockIdx.x;            // m*64 + s
    int m = bidx >> 6, s = bidx & 63;
    int fw = m & 1, fh = (m >> 1) & 1, fc = (m >> 2) & 7, n = m >> 5;
    int ci = s >> 3, cj = s & 7;
    int t = threadIdx.x;
    for (int i = t; i < 256 * 64; i += 256) {
        int c = i >> 6, p = i & 63;
        int a = p >> 3, b2 = p & 7;
        int hh = fh * 64 + ci * 8 + a, ww = fw * 64 + cj * 8 + b2;
        xs[c][p] = x[((size_t)(n * 256 + c) * 128 + hh) * 128 + ww];
    }
    __syncthreads();
    int ch = t & 63, g = t >> 6;      // wave = one g, ch 0..63 (xs reads broadcast)
    const float* wr = Wp + (size_t)(fc * 64 + ch) * 256;
    float bb = bp[fc * 64 + ch];
    #pragma unroll
    for (int aa = 0; aa < 2; ++aa) {
        int a = g * 2 + aa;
        float yb[8];
        #pragma unroll
        for (int b2 = 0; b2 < 8; ++b2) {
            float acc = 0.f;          // EXACT: sequential c, separate mul+add
            for (int c = 0; c < 256; ++c)
                acc = __fadd_rn(acc, __fmul_rn(wr[c], xs[c][a * 8 + b2]));
            yb[b2] = __fadd_rn(acc, bb);
        }
        tra[ch][a] = tree8(yb);
    }
    __syncthreads();
    if (t < 64) {                     // EXACT: left-fold over a, then /64
        float total = tra[t][0];
        #pragma unroll
        for (int a = 1; a < 8; ++a) total = __fadd_rn(total, tra[t][a]);
        CB[((size_t)m * 64 + s) * 64 + t] = __fdiv_rn(total, 64.0f);
    }
}

// ---- kNC: verbatim (bit-frozen) ----
__global__ __launch_bounds__(64) void kNC(
    const float* __restrict__ CB, float* __restrict__ NCB)
{
    int m = blockIdx.x, s = threadIdx.x;
    const float* row = CB + ((size_t)m * 64 + s) * 64;
    float sq[32];
    #pragma unroll
    for (int k = 0; k < 32; ++k) sq[k] = __fmul_rn(row[k], row[k]);
    float n2 = pw32(sq);
    float nr = __fsqrt_rn(n2);
    float mx = fmaxf(nr, 1e-12f);
    #pragma unroll
    for (int k = 0; k < 32; ++k)
        NCB[((size_t)m * 64 + s) * 32 + k] = __fdiv_rn(row[k], mx);
}

// ---- kSim: verbatim (bit-frozen) ----
__global__ __launch_bounds__(256) void kSim(
    const float* __restrict__ x, const float* __restrict__ Wp,
    const float* __restrict__ bp, const float* __restrict__ NCB,
    const float* __restrict__ alphap, const float* __restrict__ betap,
    float* __restrict__ MAXV, int* __restrict__ MAXI)
{
    __shared__ float wpl[32][256];    // 32 KiB
    __shared__ float ncl[64 * 32];    // 8 KiB
    int b = blockIdx.x;               // 1024 = m*4 + q
    int m = b >> 2, q = b & 3;
    int fw = m & 1, fh = (m >> 1) & 1, fc = (m >> 2) & 7, n = m >> 5;
    int t = threadIdx.x;
    for (int i = t; i < 32 * 256; i += 256) {
        int k = i >> 8, c = i & 255;
        wpl[k][c] = Wp[(size_t)(fc * 64 + k) * 256 + c];
    }
    for (int i = t; i < 2048; i += 256) ncl[i] = NCB[(size_t)m * 2048 + i];
    __syncthreads();

    float al = alphap[0], be = betap[0];
    for (int it = 0; it < 4; ++it) {
        int l = q * 1024 + it * 256 + t;
        int sh = l >> 6, sw = l & 63;
        int hh = fh * 64 + sh, ww = fw * 64 + sw;
        const float* pxp = x + (((size_t)(n * 256) * 128 + hh) * 128 + ww);
        float xp[32];
        #pragma unroll
        for (int k = 0; k < 32; ++k) xp[k] = 0.f;
        for (int c = 0; c < 256; ++c) {
            float xv = pxp[(size_t)c * 16384];
            #pragma unroll
            for (int k = 0; k < 32; ++k)
                xp[k] = __fadd_rn(xp[k], __fmul_rn(wpl[k][c], xv));
        }
        #pragma unroll
        for (int k = 0; k < 32; ++k) xp[k] = __fadd_rn(xp[k], bp[fc * 64 + k]);
        float sq[32];
        #pragma unroll
        for (int k = 0; k < 32; ++k) sq[k] = __fmul_rn(xp[k], xp[k]);
        float nr = __fsqrt_rn(pw32(sq));
        float mx = fmaxf(nr, 1e-12f);
        float nx[32];
        #pragma unroll
        for (int k = 0; k < 32; ++k) nx[k] = __fdiv_rn(xp[k], mx);

        float best = -3.0e38f; int bi = 0;
        for (int s = 0; s < 64; ++s) {
            float dot = dot32_sse(nx, ncl + s * 32);
            if (dot > best) { best = dot; bi = s; }
        }
        float z = __fadd_rn(__fmul_rn(al, best), be);
        float e = (float)exp(-(double)z);
        float den = __fadd_rn(1.0f, e);
        float sv = __fdiv_rn(1.0f, den);
        MAXV[(size_t)m * 4096 + l] = sv;
        MAXI[(size_t)m * 4096 + l] = bi;
    }
}

// ---- kAgg v2: one block per m; threads = pixels; LDS atomic scatter.
//      VALUE PATH (2% tolerance): FMA + atomics, order-free. ----
__global__ __launch_bounds__(256) void kAgg(
    const float* __restrict__ x, const float* __restrict__ Wp,
    const float* __restrict__ bp, const float* __restrict__ CB,
    const float* __restrict__ MAXV, const int* __restrict__ MAXI,
    float* __restrict__ AGG)
{
    __shared__ float wvl[32][256];    // value weights [v][c]  32 KiB
    __shared__ float bpv[32];
    __shared__ float ag[64 * 33];     // [s][value32 + weight] 8.25 KiB
    int m = blockIdx.x;
    int fw = m & 1, fh = (m >> 1) & 1, fc = (m >> 2) & 7, n = m >> 5;
    int t = threadIdx.x;
    for (int i = t; i < 32 * 256; i += 256) {
        int k = i >> 8, c = i & 255;
        wvl[k][c] = Wp[(size_t)(fc * 64 + 32 + k) * 256 + c];
    }
    if (t < 32) bpv[t] = bp[fc * 64 + 32 + t];
    for (int i = t; i < 64 * 33; i += 256) {
        int s = i / 33, v = i - s * 33;
        ag[i] = (v < 32) ? CB[((size_t)m * 64 + s) * 64 + 32 + v] : 1.0f;
    }
    __syncthreads();
    for (int it = 0; it < 16; ++it) {
        int l = it * 256 + t;
        int sh = l >> 6, sw = l & 63;
        int hh = fh * 64 + sh, ww = fw * 64 + sw;
        const float* pxp = x + (((size_t)(n * 256) * 128 + hh) * 128 + ww);
        float yv[32];
        #pragma unroll
        for (int k = 0; k < 32; ++k) yv[k] = 0.f;
        for (int c = 0; c < 256; ++c) {
            float xv = pxp[(size_t)c * 16384];      // coalesced across lanes
            #pragma unroll
            for (int k = 0; k < 32; ++k)
                yv[k] = __builtin_fmaf(wvl[k][c], xv, yv[k]);
        }
        float mv = MAXV[(size_t)m * 4096 + l];
        int s = MAXI[(size_t)m * 4096 + l];
        float* row = ag + s * 33;                   // 33 ≡ 1 (mod 32): s -> bank s%32
        #pragma unroll
        for (int k = 0; k < 32; ++k)
            atomicAdd(&row[k], mv * (yv[k] + bpv[k]));
        atomicAdd(&row[32], mv);
    }
    __syncthreads();
    for (int i = t; i < 2048; i += 256) {
        int s = i >> 5, v = i & 31;
        AGG[(size_t)m * 2048 + i] = __fdiv_rn(ag[s * 33 + v], ag[s * 33 + 32]);
    }
}

// ---- kOut: verbatim ----
__global__ __launch_bounds__(256) void kOut(
    const float* __restrict__ AGG, const float* __restrict__ MAXV,
    const int* __restrict__ MAXI, const float* __restrict__ Wm,
    const float* __restrict__ bm, float* __restrict__ out)
{
    __shared__ float dsp[256 * 64];   // [c2 = fc*32+v][px]  64 KiB
    int b = blockIdx.x;               // 2048 = n*256 + h*2 + fw
    int n = b >> 8; int rem = b & 255;
    int h = rem >> 1, fw = rem & 1;
    int fh = h >> 6, sh = h & 63;
    int t = threadIdx.x;
    for (int rep = 0; rep < 2; ++rep) {
        int pair = rep * 256 + t;     // fc(8) * px(64)
        int fc = pair >> 6, px = pair & 63;
        int m = ((n * 8 + fc) * 2 + fh) * 2 + fw;
        int l = sh * 64 + px;
        float mv = MAXV[(size_t)m * 4096 + l];
        int s = MAXI[(size_t)m * 4096 + l];
        const float* ar = AGG + ((size_t)m * 64 + s) * 32;
        #pragma unroll
        for (int v = 0; v < 32; ++v)
            dsp[(fc * 32 + v) * 64 + px] = __fmul_rn(mv, ar[v]);
    }
    __syncthreads();
    int d = t;
    float a[64];
    #pragma unroll
    for (int p = 0; p < 64; ++p) a[p] = 0.f;
    const float* wr = Wm + (size_t)d * 256;
    for (int c = 0; c < 256; ++c) {
        float wv = wr[c];
        const float* row = dsp + c * 64;
        #pragma unroll
        for (int p = 0; p < 64; ++p)
            a[p] = __fadd_rn(a[p], __fmul_rn(wv, row[p]));
    }
    float bb = bm[d];
    float* orow = out + ((size_t)(n * 256 + d) * 128 + h) * 128 + fw * 64;
    for (int p = 0; p < 64; ++p)
        orow[p] = __fadd_rn(a[p], bb);
}

extern "C" void kernel_launch(void* const* d_in, const int* in_sizes, int n_in,
                              void* d_out, int out_size, void* d_ws, size_t ws_size,
                              hipStream_t stream)
{
    const float* x     = (const float*)d_in[0];
    const float* Wp    = (const float*)d_in[1];
    const float* bp    = (const float*)d_in[2];
    const float* Wm    = (const float*)d_in[3];
    const float* bm    = (const float*)d_in[4];
    const float* alpha = (const float*)d_in[5];
    const float* beta  = (const float*)d_in[6];
    float* out = (float*)d_out;

    float* CB   = (float*)d_ws;                   // 1048576
    float* NCB  = CB + 1048576;                   // 524288
    float* MAXV = NCB + 524288;                   // 1048576
    int*   MAXI = (int*)(MAXV + 1048576);         // 1048576
    float* AGG  = (float*)(MAXI + 1048576);       // 524288

    hipLaunchKernelGGL(kCB,  dim3(16384), dim3(256), 0, stream, x, Wp, bp, CB);
    hipLaunchKernelGGL(kNC,  dim3(256),   dim3(64),  0, stream, CB, NCB);
    hipLaunchKernelGGL(kSim, dim3(1024),  dim3(256), 0, stream, x, Wp, bp, NCB, alpha, beta, MAXV, MAXI);
    hipLaunchKernelGGL(kAgg, dim3(256),   dim3(256), 0, stream, x, Wp, bp, CB, MAXV, MAXI, AGG);
    hipLaunchKernelGGL(kOut, dim3(2048),  dim3(256), 0, stream, AGG, MAXV, MAXI, Wm, bm, out);
}

// Round 14
// 2735.113 us; speedup vs baseline: 8.7377x; 3.3248x over previous
//
#include <hip/hip_runtime.h>
#include <math.h>

// Round 14 = Round 13 (PASSED, 9.09 ms) + structural: materialize Y once.
//  - kY: the exact bit-frozen chain (seq-c mul+add, then f32 bias add),
//    computed ONCE for all (m,ch,px) with scalar-load weights + LDS x tile.
//  - kCen: centers = tree8/left-fold reduction over stored Y (same op order).
//  - kSim: reads Y_pt (bit-identical xp) instead of recomputing the GEMM.
//  - kAgg: reads Y_val (value path; bias already in Y).
//  - kNC, kOut: verbatim.
//
// ORDERING-PATH INVARIANT: y = seq-c mul+add + f32 bias; center = tree8 over
// b, left-fold over a, /64; norms = pw32; nx/nc = f32 div; sim = dot32_sse
// reduce (s0+s1)+(s2+s3); argmax = FIRST max over RAW f32 sims; mv = f32
// sigmoid chain (CR exp via f64).
//
// Geometry: n=8, c=256, h=128, w=128; FC=8, FH=FW=2, CS=8
// sc=64, scv=32, sh=sw=64, m=256, l=4096, s=64
//
// Workspace (285 MiB):
//   Y    f32 [m][64][4096] = 67108864   (bias included)
//   CB   f32 [m][64s][64ch] = 1048576
//   NCB  f32 [m][64s][32]   = 524288
//   MAXV f32 [m][4096]      = 1048576
//   MAXI i32 [m][4096]      = 1048576
//   AGG  f32 [m][64s][32]   = 524288

__device__ __forceinline__ float tree8(const float* a) {
    float t01 = __fadd_rn(a[0], a[1]);
    float t23 = __fadd_rn(a[2], a[3]);
    float t45 = __fadd_rn(a[4], a[5]);
    float t67 = __fadd_rn(a[6], a[7]);
    return __fadd_rn(__fadd_rn(t01, t23), __fadd_rn(t45, t67));
}
__device__ __forceinline__ float pw32(const float* a) {
    float r[8];
    #pragma unroll
    for (int j = 0; j < 8; ++j) r[j] = a[j];
    #pragma unroll
    for (int i = 8; i < 32; i += 8) {
        #pragma unroll
        for (int j = 0; j < 8; ++j) r[j] = __fadd_rn(r[j], a[i + j]);
    }
    float t01 = __fadd_rn(r[0], r[1]);
    float t23 = __fadd_rn(r[2], r[3]);
    float t45 = __fadd_rn(r[4], r[5]);
    float t67 = __fadd_rn(r[6], r[7]);
    return __fadd_rn(__fadd_rn(t01, t23), __fadd_rn(t45, t67));
}
__device__ __forceinline__ float dot32_sse(const float* a, const float* b) {
    float s0 = 0.f, s1 = 0.f, s2 = 0.f, s3 = 0.f;
    #pragma unroll
    for (int k = 0; k < 32; k += 4) {
        s0 = __fadd_rn(s0, __fmul_rn(a[k + 0], b[k + 0]));
        s1 = __fadd_rn(s1, __fmul_rn(a[k + 1], b[k + 1]));
        s2 = __fadd_rn(s2, __fmul_rn(a[k + 2], b[k + 2]));
        s3 = __fadd_rn(s3, __fmul_rn(a[k + 3], b[k + 3]));
    }
    return __fadd_rn(__fadd_rn(s0, s1), __fadd_rn(s2, s3));
}

// ---- kY: Y[m][ch][px] = exact chain. Block = (n,h,fw); 256 thr; 4 passes of
//      32 channels per wave-group. Weights via wave-uniform scalar loads. ----
__global__ __launch_bounds__(256) void kY(
    const float* __restrict__ x, const float* __restrict__ Wp,
    const float* __restrict__ bp, float* __restrict__ Y)
{
    __shared__ float xs[256 * 64];          // [c][px] 64 KiB
    int b = blockIdx.x;                     // 2048 = n*256 + h*2 + fw
    int n = b >> 8; int rem = b & 255;
    int h = rem >> 1, fw = rem & 1;
    int fh = h >> 6, sh = h & 63;
    int t = threadIdx.x;
    {
        float4* xs4 = (float4*)xs;
        const float4* xsrc = (const float4*)x;
        #pragma unroll
        for (int i = 0; i < 16; ++i) {
            int id = i * 256 + t;
            int c = id >> 4, p4 = id & 15;
            size_t base = ((size_t)(n * 256 + c) * 128 + h) * 128 + fw * 64;
            xs4[id] = xsrc[base / 4 + p4];
        }
    }
    __syncthreads();
    int px = t & 63;
    int grp = __builtin_amdgcn_readfirstlane(t >> 6);   // wave-uniform
    for (int pass = 0; pass < 4; ++pass) {
        int d0 = pass * 128 + grp * 32;
        float acc[32];
        #pragma unroll
        for (int j = 0; j < 32; ++j) acc[j] = 0.f;
        const float* wbase = Wp + (size_t)d0 * 256;
        for (int c = 0; c < 256; ++c) {     // EXACT: sequential c, mul+add
            float xv = xs[c * 64 + px];
            #pragma unroll
            for (int j = 0; j < 32; ++j)
                acc[j] = __fadd_rn(acc[j], __fmul_rn(wbase[j * 256 + c], xv));
        }
        #pragma unroll
        for (int j = 0; j < 32; ++j) {
            int d = d0 + j;
            float yv = __fadd_rn(acc[j], bp[d]);        // EXACT: f32 bias add
            int fc = d >> 6, sc = d & 63;
            int m = ((n * 8 + fc) * 2 + fh) * 2 + fw;
            Y[((size_t)(m * 64 + sc)) * 4096 + sh * 64 + px] = yv;
        }
    }
}

// ---- kCen: centers from stored Y (identical op order: tree8 over b,
//      left-fold over a, /64) ----
__global__ __launch_bounds__(256) void kCen(
    const float* __restrict__ Y, float* __restrict__ CB)
{
    int m = blockIdx.x;
    int t = threadIdx.x;
    for (int i = t; i < 4096; i += 256) {
        int s = i >> 6, ch = i & 63;
        int ci = s >> 3, cj = s & 7;
        const float* yb = Y + ((size_t)(m * 64 + ch)) * 4096;
        float total = 0.f;
        #pragma unroll
        for (int a = 0; a < 8; ++a) {
            float v[8];
            #pragma unroll
            for (int b2 = 0; b2 < 8; ++b2)
                v[b2] = yb[(ci * 8 + a) * 64 + cj * 8 + b2];
            float tr = tree8(v);
            total = (a == 0) ? tr : __fadd_rn(total, tr);
        }
        CB[((size_t)m * 64 + s) * 64 + ch] = __fdiv_rn(total, 64.0f);
    }
}

// ---- kNC: verbatim (bit-frozen) ----
__global__ __launch_bounds__(64) void kNC(
    const float* __restrict__ CB, float* __restrict__ NCB)
{
    int m = blockIdx.x, s = threadIdx.x;
    const float* row = CB + ((size_t)m * 64 + s) * 64;
    float sq[32];
    #pragma unroll
    for (int k = 0; k < 32; ++k) sq[k] = __fmul_rn(row[k], row[k]);
    float n2 = pw32(sq);
    float nr = __fsqrt_rn(n2);
    float mx = fmaxf(nr, 1e-12f);
    #pragma unroll
    for (int k = 0; k < 32; ++k)
        NCB[((size_t)m * 64 + s) * 32 + k] = __fdiv_rn(row[k], mx);
}

// ---- kSim: Y_pt read (bit-identical xp, bias included) + frozen tail ----
__global__ __launch_bounds__(256) void kSim(
    const float* __restrict__ Y, const float* __restrict__ NCB,
    const float* __restrict__ alphap, const float* __restrict__ betap,
    float* __restrict__ MAXV, int* __restrict__ MAXI)
{
    __shared__ float ncl[64 * 32];    // 8 KiB
    int b = blockIdx.x;               // 1024 = m*4 + q
    int m = b >> 2, q = b & 3;
    int t = threadIdx.x;
    for (int i = t; i < 2048; i += 256) ncl[i] = NCB[(size_t)m * 2048 + i];
    __syncthreads();

    float al = alphap[0], be = betap[0];
    for (int it = 0; it < 4; ++it) {
        int l = q * 1024 + it * 256 + t;
        float xp[32];
        #pragma unroll
        for (int k = 0; k < 32; ++k)
            xp[k] = Y[((size_t)(m * 64 + k)) * 4096 + l];   // coalesced
        float sq[32];
        #pragma unroll
        for (int k = 0; k < 32; ++k) sq[k] = __fmul_rn(xp[k], xp[k]);
        float nr = __fsqrt_rn(pw32(sq));
        float mx = fmaxf(nr, 1e-12f);
        float nx[32];
        #pragma unroll
        for (int k = 0; k < 32; ++k) nx[k] = __fdiv_rn(xp[k], mx);

        float best = -3.0e38f; int bi = 0;
        for (int s = 0; s < 64; ++s) {
            float dot = dot32_sse(nx, ncl + s * 32);
            if (dot > best) { best = dot; bi = s; }
        }
        float z = __fadd_rn(__fmul_rn(al, best), be);
        float e = (float)exp(-(double)z);
        float den = __fadd_rn(1.0f, e);
        float sv = __fdiv_rn(1.0f, den);
        MAXV[(size_t)m * 4096 + l] = sv;
        MAXI[(size_t)m * 4096 + l] = bi;
    }
}

// ---- kAgg: value path; reads Y_val (bias included), LDS atomic scatter ----
__global__ __launch_bounds__(256) void kAgg(
    const float* __restrict__ Y, const float* __restrict__ CB,
    const float* __restrict__ MAXV, const int* __restrict__ MAXI,
    float* __restrict__ AGG)
{
    __shared__ float ag[64 * 33];     // [s][value32 + weight] 8.25 KiB
    int m = blockIdx.x;
    int t = threadIdx.x;
    for (int i = t; i < 64 * 33; i += 256) {
        int s = i / 33, v = i - s * 33;
        ag[i] = (v < 32) ? CB[((size_t)m * 64 + s) * 64 + 32 + v] : 1.0f;
    }
    __syncthreads();
    for (int it = 0; it < 16; ++it) {
        int l = it * 256 + t;
        float mv = MAXV[(size_t)m * 4096 + l];
        int s = MAXI[(size_t)m * 4096 + l];
        float* row = ag + s * 33;     // 33 ≡ 1 (mod 32): distinct s -> distinct bank
        #pragma unroll
        for (int k = 0; k < 32; ++k) {
            float yv = Y[((size_t)(m * 64 + 32 + k)) * 4096 + l];  // coalesced
            atomicAdd(&row[k], mv * yv);
        }
        atomicAdd(&row[32], mv);
    }
    __syncthreads();
    for (int i = t; i < 2048; i += 256) {
        int s = i >> 5, v = i & 31;
        AGG[(size_t)m * 2048 + i] = __fdiv_rn(ag[s * 33 + v], ag[s * 33 + 32]);
    }
}

// ---- kOut: verbatim ----
__global__ __launch_bounds__(256) void kOut(
    const float* __restrict__ AGG, const float* __restrict__ MAXV,
    const int* __restrict__ MAXI, const float* __restrict__ Wm,
    const float* __restrict__ bm, float* __restrict__ out)
{
    __shared__ float dsp[256 * 64];   // [c2 = fc*32+v][px]  64 KiB
    int b = blockIdx.x;               // 2048 = n*256 + h*2 + fw
    int n = b >> 8; int rem = b & 255;
    int h = rem >> 1, fw = rem & 1;
    int fh = h >> 6, sh = h & 63;
    int t = threadIdx.x;
    for (int rep = 0; rep < 2; ++rep) {
        int pair = rep * 256 + t;     // fc(8) * px(64)
        int fc = pair >> 6, px = pair & 63;
        int m = ((n * 8 + fc) * 2 + fh) * 2 + fw;
        int l = sh * 64 + px;
        float mv = MAXV[(size_t)m * 4096 + l];
        int s = MAXI[(size_t)m * 4096 + l];
        const float* ar = AGG + ((size_t)m * 64 + s) * 32;
        #pragma unroll
        for (int v = 0; v < 32; ++v)
            dsp[(fc * 32 + v) * 64 + px] = __fmul_rn(mv, ar[v]);
    }
    __syncthreads();
    int d = t;
    float a[64];
    #pragma unroll
    for (int p = 0; p < 64; ++p) a[p] = 0.f;
    const float* wr = Wm + (size_t)d * 256;
    for (int c = 0; c < 256; ++c) {
        float wv = wr[c];
        const float* row = dsp + c * 64;
        #pragma unroll
        for (int p = 0; p < 64; ++p)
            a[p] = __fadd_rn(a[p], __fmul_rn(wv, row[p]));
    }
    float bb = bm[d];
    float* orow = out + ((size_t)(n * 256 + d) * 128 + h) * 128 + fw * 64;
    for (int p = 0; p < 64; ++p)
        orow[p] = __fadd_rn(a[p], bb);
}

extern "C" void kernel_launch(void* const* d_in, const int* in_sizes, int n_in,
                              void* d_out, int out_size, void* d_ws, size_t ws_size,
                              hipStream_t stream)
{
    const float* x     = (const float*)d_in[0];
    const float* Wp    = (const float*)d_in[1];
    const float* bp    = (const float*)d_in[2];
    const float* Wm    = (const float*)d_in[3];
    const float* bm    = (const float*)d_in[4];
    const float* alpha = (const float*)d_in[5];
    const float* beta  = (const float*)d_in[6];
    float* out = (float*)d_out;

    float* Y    = (float*)d_ws;                   // 67108864
    float* CB   = Y + 67108864;                   // 1048576
    float* NCB  = CB + 1048576;                   // 524288
    float* MAXV = NCB + 524288;                   // 1048576
    int*   MAXI = (int*)(MAXV + 1048576);         // 1048576
    float* AGG  = (float*)(MAXI + 1048576);       // 524288

    hipLaunchKernelGGL(kY,   dim3(2048), dim3(256), 0, stream, x, Wp, bp, Y);
    hipLaunchKernelGGL(kCen, dim3(256),  dim3(256), 0, stream, Y, CB);
    hipLaunchKernelGGL(kNC,  dim3(256),  dim3(64),  0, stream, CB, NCB);
    hipLaunchKernelGGL(kSim, dim3(1024), dim3(256), 0, stream, Y, NCB, alpha, beta, MAXV, MAXI);
    hipLaunchKernelGGL(kAgg, dim3(256),  dim3(256), 0, stream, Y, CB, MAXV, MAXI, AGG);
    hipLaunchKernelGGL(kOut, dim3(2048), dim3(256), 0, stream, AGG, MAXV, MAXI, Wm, bm, out);
}